// Round 6
// baseline (1077.869 us; speedup 1.0000x reference)
//
#include <hip/hip_runtime.h>
#include <hip/hip_bf16.h>

#define B_ 1024
#define L_ 2048
#define C_ 32
#define O_ 2048

typedef short bf16x8 __attribute__((ext_vector_type(8)));
typedef float f32x4 __attribute__((ext_vector_type(4)));

__device__ __forceinline__ unsigned int f2bf(float f) {
    union { float f; unsigned int u; } v; v.f = f;
    unsigned int r = v.u + (0x7fffu + ((v.u >> 16) & 1u));
    return r >> 16;
}

__device__ __forceinline__ void async16(const void* g, const void* l) {
    __builtin_amdgcn_global_load_lds(
        (const __attribute__((address_space(1))) unsigned int*)g,
        (__attribute__((address_space(3))) unsigned int*)l, 16, 0, 0);
}

// ---------------- fused pre-pass ----------------
// blocks [0, 8192):   x (B,L,C) fp32 -> xT (B,C,L) bf16, LDS-staged coalesced transpose
// blocks [8192, 10240): W_pos fp32 -> bf16
__global__ __launch_bounds__(256) void k_prep(const float* __restrict__ x,
                                              unsigned short* __restrict__ xT,
                                              const float* __restrict__ wp,
                                              unsigned short* __restrict__ wpb) {
    const int t = threadIdx.x;
    if (blockIdx.x < 8192) {
        __shared__ unsigned int lds[32 * 128];
        const int b  = blockIdx.x >> 3;
        const int l0 = (blockIdx.x & 7) << 8;        // 256-l chunk
        const int c0 = (t & 7) << 2;                 // channel quad 0,4,..,28
        const int lr = (t >> 3) << 1;                // even l within 64-l group
        const float* src = x + (size_t)b * (L_ * C_) + (size_t)l0 * C_;
#pragma unroll
        for (int i = 0; i < 4; ++i) {
            const int l = i * 64 + lr;
            const float4 e = *(const float4*)(src + (size_t)l * C_ + c0);
            const float4 o = *(const float4*)(src + (size_t)(l + 1) * C_ + c0);
            const int dcol = l >> 1;
            const float ef[4] = {e.x, e.y, e.z, e.w};
            const float of[4] = {o.x, o.y, o.z, o.w};
#pragma unroll
            for (int j = 0; j < 4; ++j) {
                const int c = c0 + j;
                const unsigned int pk = f2bf(ef[j]) | (f2bf(of[j]) << 16);
                lds[c * 128 + (dcol ^ (((c >> 2) & 7) << 2))] = pk;
            }
        }
        __syncthreads();
        unsigned short* dst = xT + (size_t)b * (C_ * L_) + l0;
#pragma unroll
        for (int i = 0; i < 4; ++i) {
            const int f  = i * 256 + t;
            const int c  = f >> 5;
            const int lq = f & 31;
            const int k  = (c >> 2) & 7;
            const unsigned int* s = &lds[c * 128 + ((lq ^ k) << 2)];
            uint4 q; q.x = s[0]; q.y = s[1]; q.z = s[2]; q.w = s[3];
            *(uint4*)(dst + (size_t)c * L_ + lq * 8) = q;
        }
    } else {
        const size_t i = ((size_t)(blockIdx.x - 8192) * 256 + t) * 8;
        float4 v0 = *(const float4*)(wp + i);
        float4 v1 = *(const float4*)(wp + i + 4);
        uint4 q;
        q.x = f2bf(v0.x) | (f2bf(v0.y) << 16);
        q.y = f2bf(v0.z) | (f2bf(v0.w) << 16);
        q.z = f2bf(v1.x) | (f2bf(v1.y) << 16);
        q.w = f2bf(v1.z) | (f2bf(v1.w) << 16);
        *(uint4*)(wpb + i) = q;
    }
}

// ---------------- main GEMM: 256x256, BK=64; A via LDS, B global->regs (1-tile prefetch) ----------------
// A = xT (32768 x 2048 bf16, rows r = b*32+c), B^T = Wp (2048 x 2048 bf16).
// LDS = A only (2 bufs x 32 KB). B fragments loaded straight to VGPR, double-buffered
// one tile ahead (compiler emits exact counted vmcnt for them). Manual vmcnt(8) at the
// tile boundary drains only the 4 A-staging global_load_lds (issued first; order pinned).

#define BAR() __builtin_amdgcn_s_barrier()
#define SPIN() __builtin_amdgcn_sched_barrier(0)
#define VMW(N) asm volatile("s_waitcnt vmcnt(" #N ")" ::: "memory")
#define PRIO1() __builtin_amdgcn_s_setprio(1)
#define PRIO0() __builtin_amdgcn_s_setprio(0)

#define STG_AT(buf, tk) do { \
    async16(A + offA + (size_t)(tk) * 64,         (char*)As + (buf) * 32768 + stgo); \
    async16(A + offA + (size_t)(tk) * 64 + 16384, (char*)As + (buf) * 32768 + stgo + 1024); \
    async16(A + offA + (size_t)(tk) * 64 + 32768, (char*)As + (buf) * 32768 + 16384 + stgo); \
    async16(A + offA + (size_t)(tk) * 64 + 49152, (char*)As + (buf) * 32768 + 16384 + stgo + 1024); } while (0)

#define GBQ(be, bo, tk) do { \
    _Pragma("unroll") for (int q_ = 0; q_ < 2; ++q_) \
    _Pragma("unroll") for (int ks_ = 0; ks_ < 2; ++ks_) { \
        be[q_][ks_] = *(const bf16x8*)(Wp + gbE[q_] + (size_t)(tk) * 64 + ks_ * 32); \
        bo[q_][ks_] = *(const bf16x8*)(Wp + gbO[q_] + (size_t)(tk) * 64 + ks_ * 32); } } while (0)

#define RD_A(buf, am, dst) do { \
    _Pragma("unroll") for (int p_ = 0; p_ < 4; ++p_) { \
        const char* ap_ = (const char*)As + (buf) * 32768 + (am) * 16384 + rowA[p_]; \
        dst[p_][0] = *(const bf16x8*)(ap_ + kof0); \
        dst[p_][1] = *(const bf16x8*)(ap_ + kof1); } } while (0)

#define MMX(asrc, am, bn, bsrc) do { \
    _Pragma("unroll") for (int p_ = 0; p_ < 4; ++p_) \
    _Pragma("unroll") for (int q_ = 0; q_ < 2; ++q_) \
    _Pragma("unroll") for (int ks_ = 0; ks_ < 2; ++ks_) \
        acc[2 * p_ + (am)][2 * q_ + (bn)] = __builtin_amdgcn_mfma_f32_16x16x32_bf16( \
            asrc[p_][ks_], bsrc[q_][ks_], acc[2 * p_ + (am)][2 * q_ + (bn)], 0, 0, 0); } while (0)

// one K-tile: compute T from buf/(ce,co); stage A(T+1)->buf^1; load B(T+1)->(ne,no)
#define BODY(T, buf, ce, co, ne, no) do { \
    STG_AT((buf) ^ 1, (T) + 1); SPIN(); \
    GBQ(ne, no, (T) + 1); SPIN(); \
    RD_A(buf, 0, afa); RD_A(buf, 1, afb); \
    PRIO1(); MMX(afa, 0, 0, ce); PRIO0(); \
    PRIO1(); MMX(afa, 0, 1, co); PRIO0(); \
    PRIO1(); MMX(afb, 1, 0, ce); PRIO0(); \
    PRIO1(); MMX(afb, 1, 1, co); PRIO0(); \
    VMW(8); BAR(); SPIN(); \
} while (0)

__global__ __launch_bounds__(512, 2) void k_gemm(const unsigned short* __restrict__ A,
                                                 const unsigned short* __restrict__ Wp,
                                                 const float* __restrict__ Wc,
                                                 float* __restrict__ out) {
    __shared__ unsigned short As[2][2][8192];   // [buf][16-row-block-parity half][128 x 64]
    const int blk = blockIdx.x;
    // XCD grouping (grid 1024 % 8 == 0, bijective): the 8 nt-blocks of one mt share an XCD
    const int nt = (blk >> 3) & 7;
    const int mt = ((blk >> 6) << 3) | (blk & 7);
    const int t = threadIdx.x, lane = t & 63, w = t >> 6;
    const int wm = w >> 2, wn = w & 3;
    const int quad = lane >> 4, c16 = lane & 15;

    // A staging (global_load_lds, linear dest, source kgroup-swizzled)
    const int s_ = lane >> 3, kg = lane & 7;
    const int kgs = (kg ^ s_) << 3;
    const size_t offA = (size_t)((mt << 8) + (w << 5) + s_) * 2048 + kgs;
    const int stgo = w << 11;

    // A fragment read addressing (swizzled LDS)
    int rowA[4];
#pragma unroll
    for (int p = 0; p < 4; ++p) rowA[p] = ((((wm << 2) + p) << 4) | c16) << 7;
    const int sw = c16 & 7;
    const int kof0 = (quad ^ sw) << 4;
    const int kof1 = ((4 + quad) ^ sw) << 4;

    // B global fragment addressing: col = nt*256 + wn*64 + q*32 + bn*16 + c16
    size_t gbE[2], gbO[2];
#pragma unroll
    for (int q = 0; q < 2; ++q) {
        const int colq = (nt << 8) + (wn << 6) + (q << 5) + c16;
        gbE[q] = (size_t)colq * 2048 + (quad << 3);
        gbO[q] = (size_t)(colq + 16) * 2048 + (quad << 3);
    }

    bf16x8 afa[4][2], afb[4][2];
    bf16x8 be0[2][2], bo0[2][2], be1[2][2], bo1[2][2];
    f32x4 acc[8][4] = {};

    // prologue: stage A tile0 -> buf0 (4 async16, first in vm queue), load B tile0
    STG_AT(0, 0); SPIN();
    GBQ(be0, bo0, 0); SPIN();
    VMW(8); BAR(); SPIN();          // drains the 4 A-stage ops; B0 stays in flight

    for (int I = 0; I < 15; ++I) {
        BODY(2 * I,     0, be0, bo0, be1, bo1);
        BODY(2 * I + 1, 1, be1, bo1, be0, bo0);
    }
    BODY(30, 0, be0, bo0, be1, bo1);   // stages A(31)->buf1, loads B(31)->set1

    // tail: tile 31 from buf1 / set1 (no staging, no boundary)
    RD_A(1, 0, afa); RD_A(1, 1, afb);
    PRIO1(); MMX(afa, 0, 0, be1); PRIO0();
    PRIO1(); MMX(afa, 0, 1, bo1); PRIO0();
    PRIO1(); MMX(afb, 1, 0, be1); PRIO0();
    PRIO1(); MMX(afb, 1, 1, bo1); PRIO0();

    // ---- epilogue: weighted c-reduction, out[b,o] = sum_c Wc[o,c]*u[(b,c),o] ----
    // acc[2p+am][ni]: b = mt*8 + wm*4 + p, c = am*16 + quad*4 + reg, o = colW + ni*16 + c16
    const int colW = (nt << 8) + (wn << 6);
#pragma unroll
    for (int p = 0; p < 4; ++p) {
        const int bg = (mt << 3) + (wm << 2) + p;
#pragma unroll
        for (int ni = 0; ni < 4; ++ni) {
            const int o = colW + (ni << 4) + c16;
            const f32x4 w0 = *(const f32x4*)(Wc + o * 32 + quad * 4);
            const f32x4 w1 = *(const f32x4*)(Wc + o * 32 + 16 + quad * 4);
            const f32x4 aA = acc[2 * p][ni];
            const f32x4 aB = acc[2 * p + 1][ni];
            float sv = aA[0] * w0[0] + aA[1] * w0[1] + aA[2] * w0[2] + aA[3] * w0[3]
                     + aB[0] * w1[0] + aB[1] * w1[1] + aB[2] * w1[2] + aB[3] * w1[3];
            sv += __shfl_xor(sv, 16, 64);
            sv += __shfl_xor(sv, 32, 64);
            if (quad == 0) out[(size_t)bg * O_ + o] = sv;
        }
    }
}

// ---------------- fallback (only if ws too small): fp32 VALU, slow but correct ----------------
__global__ __launch_bounds__(256) void k_fallback(const float* __restrict__ x,
                                                  const float* __restrict__ wpos,
                                                  const float* __restrict__ wchan,
                                                  float* __restrict__ out) {
    __shared__ float xs[128 * 32];
    const int b = blockIdx.x >> 3;
    const int o = ((blockIdx.x & 7) << 8) + threadIdx.x;
    float wc[32];
#pragma unroll
    for (int c = 0; c < 32; ++c) wc[c] = wchan[o * 32 + c];
    float acc = 0.f;
    for (int l0 = 0; l0 < 2048; l0 += 128) {
        __syncthreads();
#pragma unroll
        for (int i = 0; i < 16; ++i) {
            int f = i * 256 + threadIdx.x;
            xs[f] = x[(size_t)b * 65536 + (size_t)l0 * 32 + f];
        }
        __syncthreads();
        for (int l = 0; l < 128; ++l) {
            float wp = wpos[(size_t)o * 2048 + l0 + l];
            float s = 0.f;
#pragma unroll
            for (int c = 0; c < 32; ++c) s += xs[l * 32 + c] * wc[c];
            acc += wp * s;
        }
    }
    out[(size_t)b * 2048 + o] = acc;
}

extern "C" void kernel_launch(void* const* d_in, const int* in_sizes, int n_in,
                              void* d_out, int out_size, void* d_ws, size_t ws_size,
                              hipStream_t stream) {
    const float* x     = (const float*)d_in[0];
    const float* wpos  = (const float*)d_in[1];
    const float* wchan = (const float*)d_in[2];
    float* out = (float*)d_out;

    const size_t xT_bytes = (size_t)B_ * C_ * L_ * 2;   // 128 MiB
    const size_t wp_bytes = (size_t)O_ * L_ * 2;        // 8 MiB

    if (ws_size >= xT_bytes + wp_bytes) {
        unsigned short* xT  = (unsigned short*)d_ws;
        unsigned short* wpb = (unsigned short*)((char*)d_ws + xT_bytes);
        k_prep<<<8192 + 2048, 256, 0, stream>>>(x, xT, wpos, wpb);
        k_gemm<<<(B_ * C_ / 256) * (O_ / 256), 512, 0, stream>>>(xT, wpb, wchan, out);
    } else {
        k_fallback<<<B_ * 8, 256, 0, stream>>>(x, wpos, wchan, out);
    }
}